// Round 19
// baseline (330.352 us; speedup 1.0000x reference)
//
#include <hip/hip_runtime.h>
#include <math.h>

#define NEG_SLOPE_F 0.2f
#define NB    256     // dst buckets
#define NBLK  512     // binning chunk blocks
#define OSCAP 3328    // LDS cap >= chunk = ceil((E+N)/NBLK)

typedef __attribute__((ext_vector_type(8)))  short short8;
typedef __attribute__((ext_vector_type(16))) float f32x16;

static __device__ __forceinline__ float lrelu(float x) {
    return x > 0.f ? x : NEG_SLOPE_F * x;
}
static __device__ __forceinline__ unsigned f2bf(float f) {
    unsigned u = __float_as_uint(f);
    return (u + 0x7FFFu + ((u >> 16) & 1u)) >> 16;
}
static __device__ __forceinline__ float bflo(unsigned w) { return __uint_as_float(w << 16); }
static __device__ __forceinline__ float bfhi(unsigned w) { return __uint_as_float(w & 0xFFFF0000u); }

static __device__ __forceinline__ int bucket_of(int d, int nps, float inv_nps) {
    int b = (int)((float)d * inv_nps);
    if (d < b * nps) --b;
    else if (d >= (b + 1) * nps) ++b;
    return b;
}

// ---------------- fused L1: countSort (blocks [0,NBLK)) + MFMA GEMM ---------
// sort: one global pass -> LDS stage+hist, LDS scatter, coalesced stream-out.
// gemm: h written GROUP-MAJOR: hg[g][n][16] bf16 (g = dim/16). Each group's
// slice is a contiguous 3.2MB region -> L2-resident per XCD in k_agg.
__global__ __launch_bounds__(256) void k_gemm_sortA(
        const float* __restrict__ x, const float* __restrict__ W,
        unsigned short* __restrict__ h, int M,
        const int* __restrict__ ei, int E, int N, int nps, float inv_nps,
        int* __restrict__ cntT, int* __restrict__ fragRow,
        unsigned* __restrict__ pairs, int chunk) {
    int bid = (int)blockIdx.x;
    int tid = threadIdx.x;

    if (bid < NBLK) {
        // ---- counting sort of this block's edge chunk ----
        __shared__ unsigned stage[OSCAP];
        __shared__ unsigned osort[OSCAP];
        __shared__ unsigned char sbkt[OSCAP];
        __shared__ int hist[NB];
        __shared__ int sm[NB];
        __shared__ int cur[NB];
        hist[tid] = 0;
        __syncthreads();
        int total = E + N;
        int lo = bid * chunk;
        int hi = lo + chunk; if (hi > total) hi = total;
        int cnt = hi - lo;
        for (int j = tid; j < cnt; j += 256) {
            int t = lo + j;
            int s, d;
            if (t < E) { s = ei[t]; d = ei[E + t]; }
            else       { s = t - E; d = s; }
            unsigned pk = 0xFFFFFFFFu;
            int b = 0;
            if ((unsigned)s < (unsigned)N && (unsigned)d < (unsigned)N) {
                b = bucket_of(d, nps, inv_nps);
                pk = ((unsigned)s << 9) | (unsigned)(d - b * nps);
                atomicAdd(&hist[b], 1);
            }
            stage[j] = pk;
            sbkt[j] = (unsigned char)b;
        }
        __syncthreads();
        int v = hist[tid];
        sm[tid] = v;
        __syncthreads();
        int acc = v;
        for (int off = 1; off < 256; off <<= 1) {
            int o = (tid >= (unsigned)off) ? sm[tid - off] : 0;
            __syncthreads();
            acc += o; sm[tid] = acc; __syncthreads();
        }
        int excl = acc - v;
        fragRow[bid * NB + tid] = excl;
        cntT[tid * NBLK + bid] = v;
        cur[tid] = excl;
        __syncthreads();
        for (int j = tid; j < cnt; j += 256) {
            unsigned pk = stage[j];
            if (pk == 0xFFFFFFFFu) continue;
            int b = sbkt[j];
            int pos = atomicAdd(&cur[b], 1);
            osort[pos] = pk;
        }
        __syncthreads();
        int m = cur[NB - 1];
        unsigned* pout = pairs + (size_t)bid * chunk;
        for (int j = tid; j < m; j += 256)
            pout[j] = osort[j];
        return;
    }

    // ---- MFMA GEMM: 128x128 per block, W read direct, hg-layout writes ----
    int gb = bid - NBLK;
    int w = tid >> 6;
    int lane = tid & 63;
    int l31 = lane & 31;
    int lh = lane >> 5;
    int row0 = gb * 128 + w * 32;

    f32x16 acc0, acc1, acc2, acc3;
#pragma unroll
    for (int i = 0; i < 16; ++i) { acc0[i] = 0.f; acc1[i] = 0.f; acc2[i] = 0.f; acc3[i] = 0.f; }

    int arow = row0 + l31;
    if (arow >= M) arow = M - 1;

    for (int k0 = 0; k0 < 128; k0 += 16) {
        int kb = k0 + lh * 8;
        float4 v0 = *(const float4*)&x[(size_t)arow * 128 + kb];
        float4 v1 = *(const float4*)&x[(size_t)arow * 128 + kb + 4];
        short8 a;
        a[0] = (short)f2bf(v0.x); a[1] = (short)f2bf(v0.y);
        a[2] = (short)f2bf(v0.z); a[3] = (short)f2bf(v0.w);
        a[4] = (short)f2bf(v1.x); a[5] = (short)f2bf(v1.y);
        a[6] = (short)f2bf(v1.z); a[7] = (short)f2bf(v1.w);
        short8 b0, b1, b2, b3;
#pragma unroll
        for (int j = 0; j < 8; ++j) {
            const float* wr = &W[(size_t)(kb + j) * 128];
            b0[j] = (short)f2bf(wr[  0 + l31]);
            b1[j] = (short)f2bf(wr[ 32 + l31]);
            b2[j] = (short)f2bf(wr[ 64 + l31]);
            b3[j] = (short)f2bf(wr[ 96 + l31]);
        }
        acc0 = __builtin_amdgcn_mfma_f32_32x32x16_bf16(a, b0, acc0, 0, 0, 0);
        acc1 = __builtin_amdgcn_mfma_f32_32x32x16_bf16(a, b1, acc1, 0, 0, 0);
        acc2 = __builtin_amdgcn_mfma_f32_32x32x16_bf16(a, b2, acc2, 0, 0, 0);
        acc3 = __builtin_amdgcn_mfma_f32_32x32x16_bf16(a, b3, acc3, 0, 0, 0);
    }
    // hg layout: dim = 32q + l31 -> group = 2q + (l31>>4), off = l31&15
    int ghi = l31 >> 4;
    int off16 = l31 & 15;
#pragma unroll
    for (int reg = 0; reg < 16; ++reg) {
        int row = row0 + (reg & 3) + 8 * (reg >> 2) + 4 * lh;
        if (row < M) {
            h[((size_t)(0 + ghi) * M + row) * 16 + off16] = (unsigned short)f2bf(acc0[reg]);
            h[((size_t)(2 + ghi) * M + row) * 16 + off16] = (unsigned short)f2bf(acc1[reg]);
            h[((size_t)(4 + ghi) * M + row) * 16 + off16] = (unsigned short)f2bf(acc2[reg]);
            h[((size_t)(6 + ghi) * M + row) * 16 + off16] = (unsigned short)f2bf(acc3[reg]);
        }
    }
}

// ---------------- fused L2: binB (2 fragments/thread) + att ----------------
__global__ __launch_bounds__(256) void k_binB_att(
        const unsigned* __restrict__ pairs,
        const int* __restrict__ cntT, const int* __restrict__ fragRow,
        int* __restrict__ csrc, int* __restrict__ rowptr,
        const unsigned short* __restrict__ h,
        const float* __restrict__ att_s, const float* __restrict__ att_d,
        float* __restrict__ as, float* __restrict__ ad,
        int N, int nps, int chunk) {
    int bid = (int)blockIdx.x;
    int t = threadIdx.x;

    if (bid >= NB) {
        // ---- att role (hg layout: dims 2j,2j+1 -> group j>>3, word j&7) ----
        int g = (bid - NB) * 256 + t;
        int n = g >> 6;
        int j = g & 63;
        if (n >= N) return;
        unsigned u = ((const unsigned*)h)[((size_t)(j >> 3) * N + n) * 8 + (j & 7)];
        float lo = bflo(u), hi = bfhi(u);
        float ps = lo * att_s[2 * j] + hi * att_s[2 * j + 1];
        float pd = lo * att_d[2 * j] + hi * att_d[2 * j + 1];
#pragma unroll
        for (int off = 8; off >= 1; off >>= 1) {
            ps += __shfl_xor(ps, off, 64);
            pd += __shfl_xor(pd, off, 64);
        }
        if ((j & 15) == 0) {
            int hh = j >> 4;
            as[n * 4 + hh] = ps;
            ad[n * 4 + hh] = pd;
        }
        return;
    }

    // ---- binB role ----
    __shared__ int hist[512];
    __shared__ int rpt[512];
    __shared__ int sm[256];
    __shared__ int tot_s;
    int b = bid;

    int partial = 0;
#pragma unroll 8
    for (int bp = 0; bp < b; ++bp)
        partial += cntT[bp * NBLK + t] + cntT[bp * NBLK + t + 256];
    sm[t] = partial;
    __syncthreads();
    for (int off = 128; off >= 1; off >>= 1) {
        if (t < off) sm[t] += sm[t + off];
        __syncthreads();
    }
    int bbase = sm[0];
    __syncthreads();

    hist[t] = 0; hist[t + 256] = 0;
    __syncthreads();

    int fo0 = t * chunk + fragRow[t * NB + b];
    int fc0 = cntT[b * NBLK + t];
    int fo1 = (t + 256) * chunk + fragRow[(t + 256) * NB + b];
    int fc1 = cntT[b * NBLK + t + 256];

    for (int j = 0; j < fc0; ++j)
        atomicAdd(&hist[pairs[(size_t)fo0 + j] & 511], 1);
    for (int j = 0; j < fc1; ++j)
        atomicAdd(&hist[pairs[(size_t)fo1 + j] & 511], 1);
    __syncthreads();

    int e0 = hist[2 * t], e1 = hist[2 * t + 1];
    int ps2 = e0 + e1;
    sm[t] = ps2;
    __syncthreads();
    int acc = ps2;
    for (int off = 1; off < 256; off <<= 1) {
        int o = (t >= (unsigned)off) ? sm[t - off] : 0;
        __syncthreads();
        acc += o; sm[t] = acc; __syncthreads();
    }
    int excl = acc - ps2;
    rpt[2 * t] = excl;
    rpt[2 * t + 1] = excl + e0;
    if (t == 255) tot_s = excl + e0 + e1;
    __syncthreads();
    hist[t] = rpt[t]; hist[t + 256] = rpt[t + 256];
    __syncthreads();

    for (int j = 0; j < fc0; ++j) {
        unsigned pk = pairs[(size_t)fo0 + j];
        int pos = atomicAdd(&hist[pk & 511], 1);
        csrc[bbase + pos] = (int)(pk >> 9);
    }
    for (int j = 0; j < fc1; ++j) {
        unsigned pk = pairs[(size_t)fo1 + j];
        int pos = atomicAdd(&hist[pk & 511], 1);
        csrc[bbase + pos] = (int)(pk >> 9);
    }

    for (int k = t; k < nps; k += 256) {
        int n = b * nps + k;
        if (n < N) rowptr[n] = bbase + rpt[k];
    }
    if (b == NB - 1 && t == 0) rowptr[N] = bbase + tot_s;
}

// ---------------- aggregate: column-split, group = blockIdx%8 (XCD-local) ---
// Block covers 16 nodes x its 16-dim group; wave = 4 nodes, 16 edge slots x
// 4 lanes. Group slice of hg (3.2MB contiguous) is L2-resident per XCD.
__global__ __launch_bounds__(256) void k_agg(const unsigned short* __restrict__ h,
                                             const int* __restrict__ rowptr, const int* __restrict__ csrc,
                                             const float* __restrict__ as, const float* __restrict__ ad,
                                             const float* __restrict__ bias,
                                             float* __restrict__ out, int N) {
    int g = blockIdx.x & 7;            // dim group 0..7 -> XCD g (round-robin)
    int nb = blockIdx.x >> 3;
    int wv = threadIdx.x >> 6;
    int lane = threadIdx.x & 63;
    int slot = lane >> 2;              // 16 edge slots
    int q4 = lane & 3;                 // 4 dims each (of the group's 16)
    int head = g >> 1;

    const uint2* hp = (const uint2*)h; // 4 uint2 per (g,n)
    size_t gbase = (size_t)g * N;

    for (int dl = 0; dl < 4; ++dl) {
        int n = nb * 16 + wv * 4 + dl;
        if (n >= N) return;
        int o0 = rowptr[n];
        int deg = rowptr[n + 1] - o0;
        float adh = ad[(size_t)n * 4 + head];

        float a0 = 0.f, a1 = 0.f, a2 = 0.f, a3 = 0.f, sw = 0.f;
        for (int i = slot; i < deg; i += 16) {
            int s = csrc[o0 + i];
            float e = lrelu(as[(size_t)s * 4 + head] + adh);
            float w = __expf(e);
            uint2 u = hp[(gbase + s) * 4 + q4];
            a0 = fmaf(w, bflo(u.x), a0);
            a1 = fmaf(w, bfhi(u.x), a1);
            a2 = fmaf(w, bflo(u.y), a2);
            a3 = fmaf(w, bfhi(u.y), a3);
            sw += w;
        }
#pragma unroll
        for (int off = 4; off <= 32; off <<= 1) {
            a0 += __shfl_xor(a0, off, 64);
            a1 += __shfl_xor(a1, off, 64);
            a2 += __shfl_xor(a2, off, 64);
            a3 += __shfl_xor(a3, off, 64);
            sw += __shfl_xor(sw, off, 64);
        }
        if (slot == 0) {
            float inv = 1.f / (sw + 1e-16f);
            int d0 = g * 16 + q4 * 4;
            float4 bv = *(const float4*)&bias[d0];
            float r0 = fmaf(a0, inv, bv.x);
            float r1 = fmaf(a1, inv, bv.y);
            float r2 = fmaf(a2, inv, bv.z);
            float r3 = fmaf(a3, inv, bv.w);
            r0 = r0 > 0.f ? r0 : __expf(r0) - 1.f;
            r1 = r1 > 0.f ? r1 : __expf(r1) - 1.f;
            r2 = r2 > 0.f ? r2 : __expf(r2) - 1.f;
            r3 = r3 > 0.f ? r3 : __expf(r3) - 1.f;
            *(float4*)&out[(size_t)n * 128 + d0] = make_float4(r0, r1, r2, r3);
        }
    }
}

// ---------------- launch ----------------
extern "C" void kernel_launch(void* const* d_in, const int* in_sizes, int n_in,
                              void* d_out, int out_size, void* d_ws, size_t ws_size,
                              hipStream_t stream) {
    const float* x     = (const float*)d_in[0];
    const int*   ei    = (const int*)d_in[1];     // int32 [2][E] flat
    const float* W     = (const float*)d_in[2];
    const float* att_s = (const float*)d_in[3];
    const float* att_d = (const float*)d_in[4];
    const float* bias  = (const float*)d_in[5];
    float* out = (float*)d_out;

    int N = in_sizes[0] / 128;
    int E = in_sizes[1] / 2;
    int total = E + N;

    int nps = (N + NB - 1) / NB;                  // 391 (<512 for 9-bit pack)
    float inv_nps = 1.0f / (float)nps;
    int chunk = (total + NBLK - 1) / NBLK;        // ~3322 (<= OSCAP)

    auto align256 = [](size_t v) { return (v + 255) & ~(size_t)255; };
    char* wsp = (char*)d_ws;
    size_t off = 0;
    auto alloc = [&](size_t bytes) {
        char* p = wsp + off;
        off += align256(bytes);
        return p;
    };
    unsigned short* h  = (unsigned short*)alloc((size_t)N * 128 * 2);   // hg[8][N][16]
    float* as        = (float*)alloc((size_t)N * 16);
    float* ad        = (float*)alloc((size_t)N * 16);
    int*   cntT      = (int*)alloc((size_t)NB * NBLK * 4);
    int*   fragRow   = (int*)alloc((size_t)NBLK * NB * 4);
    unsigned* pairs  = (unsigned*)alloc((size_t)NBLK * chunk * 4);
    int*   csrc      = (int*)alloc((size_t)total * 4);
    int*   rowptr    = (int*)alloc((size_t)(N + 1) * 4);
    (void)ws_size;

    int nGemm = (N + 127) / 128;                  // 782
    int nAtt  = ((size_t)N * 64 + 255) / 256;     // 25000
    int nAgg  = 8 * ((N + 15) / 16);              // 50000, group = bid%8

    k_gemm_sortA<<<NBLK + nGemm, 256, 0, stream>>>(x, W, h, N, ei, E, N, nps, inv_nps,
                                                   cntT, fragRow, pairs, chunk);
    k_binB_att<<<NB + nAtt, 256, 0, stream>>>(pairs, cntT, fragRow, csrc, rowptr,
                                              h, att_s, att_d, as, ad, N, nps, chunk);
    k_agg<<<nAgg, 256, 0, stream>>>(h, rowptr, csrc, as, ad, bias, out, N);
}

// Round 20
// 308.520 us; speedup vs baseline: 1.0708x; 1.0708x over previous
//
#include <hip/hip_runtime.h>
#include <math.h>

#define NEG_SLOPE_F 0.2f
#define NB    256     // dst buckets
#define NBLK  512     // binning chunk blocks
#define OSCAP 3328    // LDS cap >= chunk = ceil((E+N)/NBLK)

typedef __attribute__((ext_vector_type(8)))  short short8;
typedef __attribute__((ext_vector_type(16))) float f32x16;

static __device__ __forceinline__ float lrelu(float x) {
    return x > 0.f ? x : NEG_SLOPE_F * x;
}
static __device__ __forceinline__ unsigned f2bf(float f) {
    unsigned u = __float_as_uint(f);
    return (u + 0x7FFFu + ((u >> 16) & 1u)) >> 16;
}
static __device__ __forceinline__ float bflo(unsigned w) { return __uint_as_float(w << 16); }
static __device__ __forceinline__ float bfhi(unsigned w) { return __uint_as_float(w & 0xFFFF0000u); }

static __device__ __forceinline__ int bucket_of(int d, int nps, float inv_nps) {
    int b = (int)((float)d * inv_nps);
    if (d < b * nps) --b;
    else if (d >= (b + 1) * nps) ++b;
    return b;
}

// ---------------- fused L1: countSort (blocks [0,NBLK)) + MFMA GEMM ---------
// sort: one global pass -> LDS stage+hist, LDS scatter, coalesced stream-out.
// gemm: h row-major bf16 (round-16 proven); as/ad computed in the epilogue
// via half-wave shfl reduction (deletes the separate att pass).
__global__ __launch_bounds__(256) void k_gemm_sortA(
        const float* __restrict__ x, const float* __restrict__ W,
        unsigned short* __restrict__ h, int M,
        const int* __restrict__ ei, int E, int N, int nps, float inv_nps,
        int* __restrict__ cntT, int* __restrict__ fragRow,
        unsigned* __restrict__ pairs, int chunk,
        const float* __restrict__ att_s, const float* __restrict__ att_d,
        float* __restrict__ as, float* __restrict__ ad) {
    int bid = (int)blockIdx.x;
    int tid = threadIdx.x;

    if (bid < NBLK) {
        // ---- counting sort of this block's edge chunk ----
        __shared__ unsigned stage[OSCAP];
        __shared__ unsigned osort[OSCAP];
        __shared__ unsigned char sbkt[OSCAP];
        __shared__ int hist[NB];
        __shared__ int sm[NB];
        __shared__ int cur[NB];
        hist[tid] = 0;
        __syncthreads();
        int total = E + N;
        int lo = bid * chunk;
        int hi = lo + chunk; if (hi > total) hi = total;
        int cnt = hi - lo;
        for (int j = tid; j < cnt; j += 256) {
            int t = lo + j;
            int s, d;
            if (t < E) { s = ei[t]; d = ei[E + t]; }
            else       { s = t - E; d = s; }
            unsigned pk = 0xFFFFFFFFu;
            int b = 0;
            if ((unsigned)s < (unsigned)N && (unsigned)d < (unsigned)N) {
                b = bucket_of(d, nps, inv_nps);
                pk = ((unsigned)s << 9) | (unsigned)(d - b * nps);
                atomicAdd(&hist[b], 1);
            }
            stage[j] = pk;
            sbkt[j] = (unsigned char)b;
        }
        __syncthreads();
        int v = hist[tid];
        sm[tid] = v;
        __syncthreads();
        int acc = v;
        for (int off = 1; off < 256; off <<= 1) {
            int o = (tid >= (unsigned)off) ? sm[tid - off] : 0;
            __syncthreads();
            acc += o; sm[tid] = acc; __syncthreads();
        }
        int excl = acc - v;
        fragRow[bid * NB + tid] = excl;
        cntT[tid * NBLK + bid] = v;
        cur[tid] = excl;
        __syncthreads();
        for (int j = tid; j < cnt; j += 256) {
            unsigned pk = stage[j];
            if (pk == 0xFFFFFFFFu) continue;
            int b = sbkt[j];
            int pos = atomicAdd(&cur[b], 1);
            osort[pos] = pk;
        }
        __syncthreads();
        int m = cur[NB - 1];
        unsigned* pout = pairs + (size_t)bid * chunk;
        for (int j = tid; j < m; j += 256)
            pout[j] = osort[j];
        return;
    }

    // ---- MFMA GEMM: 128x128 per block, 4 waves x 32 rows, W read direct ----
    int gb = bid - NBLK;
    int w = tid >> 6;
    int lane = tid & 63;
    int l31 = lane & 31;
    int lh = lane >> 5;
    int row0 = gb * 128 + w * 32;

    f32x16 acc0, acc1, acc2, acc3;
#pragma unroll
    for (int i = 0; i < 16; ++i) { acc0[i] = 0.f; acc1[i] = 0.f; acc2[i] = 0.f; acc3[i] = 0.f; }

    int arow = row0 + l31;
    if (arow >= M) arow = M - 1;

    for (int k0 = 0; k0 < 128; k0 += 16) {
        int kb = k0 + lh * 8;
        float4 v0 = *(const float4*)&x[(size_t)arow * 128 + kb];
        float4 v1 = *(const float4*)&x[(size_t)arow * 128 + kb + 4];
        short8 a;
        a[0] = (short)f2bf(v0.x); a[1] = (short)f2bf(v0.y);
        a[2] = (short)f2bf(v0.z); a[3] = (short)f2bf(v0.w);
        a[4] = (short)f2bf(v1.x); a[5] = (short)f2bf(v1.y);
        a[6] = (short)f2bf(v1.z); a[7] = (short)f2bf(v1.w);
        short8 b0, b1, b2, b3;
#pragma unroll
        for (int j = 0; j < 8; ++j) {
            const float* wr = &W[(size_t)(kb + j) * 128];
            b0[j] = (short)f2bf(wr[  0 + l31]);
            b1[j] = (short)f2bf(wr[ 32 + l31]);
            b2[j] = (short)f2bf(wr[ 64 + l31]);
            b3[j] = (short)f2bf(wr[ 96 + l31]);
        }
        acc0 = __builtin_amdgcn_mfma_f32_32x32x16_bf16(a, b0, acc0, 0, 0, 0);
        acc1 = __builtin_amdgcn_mfma_f32_32x32x16_bf16(a, b1, acc1, 0, 0, 0);
        acc2 = __builtin_amdgcn_mfma_f32_32x32x16_bf16(a, b2, acc2, 0, 0, 0);
        acc3 = __builtin_amdgcn_mfma_f32_32x32x16_bf16(a, b3, acc3, 0, 0, 0);
    }

    // epilogue: h writes + fused as/ad half-wave reduction
    float asv0 = att_s[  0 + l31], asv1 = att_s[ 32 + l31];
    float asv2 = att_s[ 64 + l31], asv3 = att_s[ 96 + l31];
    float adv0 = att_d[  0 + l31], adv1 = att_d[ 32 + l31];
    float adv2 = att_d[ 64 + l31], adv3 = att_d[ 96 + l31];

#pragma unroll
    for (int reg = 0; reg < 16; ++reg) {
        int row = row0 + (reg & 3) + 8 * (reg >> 2) + 4 * lh;
        bool ok = (row < M);
        if (ok) {
            size_t rb = (size_t)row * 128;
            h[rb +  0 + l31] = (unsigned short)f2bf(acc0[reg]);
            h[rb + 32 + l31] = (unsigned short)f2bf(acc1[reg]);
            h[rb + 64 + l31] = (unsigned short)f2bf(acc2[reg]);
            h[rb + 96 + l31] = (unsigned short)f2bf(acc3[reg]);
        }
        float ps0 = acc0[reg] * asv0, ps1 = acc1[reg] * asv1;
        float ps2 = acc2[reg] * asv2, ps3 = acc3[reg] * asv3;
        float pd0 = acc0[reg] * adv0, pd1 = acc1[reg] * adv1;
        float pd2 = acc2[reg] * adv2, pd3 = acc3[reg] * adv3;
#pragma unroll
        for (int off = 1; off <= 16; off <<= 1) {
            ps0 += __shfl_xor(ps0, off, 64); ps1 += __shfl_xor(ps1, off, 64);
            ps2 += __shfl_xor(ps2, off, 64); ps3 += __shfl_xor(ps3, off, 64);
            pd0 += __shfl_xor(pd0, off, 64); pd1 += __shfl_xor(pd1, off, 64);
            pd2 += __shfl_xor(pd2, off, 64); pd3 += __shfl_xor(pd3, off, 64);
        }
        if (l31 == 0 && ok) {
            *(float4*)&as[(size_t)row * 4] = make_float4(ps0, ps1, ps2, ps3);
            *(float4*)&ad[(size_t)row * 4] = make_float4(pd0, pd1, pd2, pd3);
        }
    }
}

// ---------------- L2: binB (512 threads, 1 fragment/thread) + w precompute --
__global__ __launch_bounds__(512) void k_binB(
        const unsigned* __restrict__ pairs,
        const int* __restrict__ cntT, const int* __restrict__ fragRow,
        int* __restrict__ csrc, uint2* __restrict__ wbuf, int* __restrict__ rowptr,
        const float* __restrict__ as, const float* __restrict__ ad,
        int N, int nps, int chunk) {
    __shared__ int hist[512];
    __shared__ int rpt[512];
    __shared__ int sm[512];
    __shared__ int tot_s;
    int b = (int)blockIdx.x;
    int t = threadIdx.x;

    // bucketBase: thread t sums column t over buckets < b, then tree-reduce
    int partial = 0;
    for (int bp = 0; bp < b; ++bp) partial += cntT[bp * NBLK + t];
    sm[t] = partial;
    __syncthreads();
    for (int off = 256; off >= 1; off >>= 1) {
        if (t < off) sm[t] += sm[t + off];
        __syncthreads();
    }
    int bbase = sm[0];
    __syncthreads();

    hist[t] = 0;
    __syncthreads();

    int fo = t * chunk + fragRow[t * NB + b];
    int fc = cntT[b * NBLK + t];

    for (int j = 0; j < fc; ++j)
        atomicAdd(&hist[pairs[(size_t)fo + j] & 511], 1);
    __syncthreads();

    int hv = hist[t];
    sm[t] = hv;
    __syncthreads();
    int acc = hv;
    for (int off = 1; off < 512; off <<= 1) {
        int o = (t >= (unsigned)off) ? sm[t - off] : 0;
        __syncthreads();
        acc += o; sm[t] = acc; __syncthreads();
    }
    int excl = acc - hv;
    rpt[t] = excl;
    if (t == 511) tot_s = acc;
    __syncthreads();
    hist[t] = excl;      // cursors
    __syncthreads();

    for (int j = 0; j < fc; ++j) {
        unsigned pk = pairs[(size_t)fo + j];
        int dl = pk & 511;
        int s = (int)(pk >> 9);
        int pos = atomicAdd(&hist[dl], 1);
        int d = b * nps + dl;
        float4 a4 = *(const float4*)&as[(size_t)s * 4];
        float4 d4 = *(const float4*)&ad[(size_t)d * 4];
        float w0 = __expf(lrelu(a4.x + d4.x));
        float w1 = __expf(lrelu(a4.y + d4.y));
        float w2 = __expf(lrelu(a4.z + d4.z));
        float w3 = __expf(lrelu(a4.w + d4.w));
        uint2 pw;
        pw.x = f2bf(w0) | (f2bf(w1) << 16);
        pw.y = f2bf(w2) | (f2bf(w3) << 16);
        csrc[bbase + pos] = s;
        wbuf[bbase + pos] = pw;
    }

    for (int k = t; k < nps; k += 512) {
        int n = b * nps + k;
        if (n < N) rowptr[n] = bbase + rpt[k];
    }
    if (b == NB - 1 && t == 0) rowptr[N] = bbase + tot_s;
}

// ---------------- aggregate: 8 edges in flight, weights from wbuf ----------
__global__ __launch_bounds__(256) void k_agg(const unsigned short* __restrict__ h,
                                             const int* __restrict__ rowptr, const int* __restrict__ csrc,
                                             const uint2* __restrict__ wbuf,
                                             const float* __restrict__ bias,
                                             float* __restrict__ out, int N) {
    int wv = threadIdx.x >> 6;
    int lane = threadIdx.x & 63;
    int n = blockIdx.x * 4 + wv;
    if (n >= N) return;
    int og = lane >> 3;            // edge slot 0..7
    int q8 = lane & 7;             // dims 16*q8 .. 16*q8+15
    int head = q8 >> 1;

    int o0 = rowptr[n];
    int deg = rowptr[n + 1] - o0;

    const uint4* hp = (const uint4*)h;   // 16 uint4 per row
    float a[16];
#pragma unroll
    for (int j = 0; j < 16; ++j) a[j] = 0.f;
    float sw = 0.f;

    for (int i = og; i < deg; i += 8) {
        int s = csrc[o0 + i];
        uint2 uw = wbuf[o0 + i];
        unsigned word = (head & 2) ? uw.y : uw.x;
        float w = (head & 1) ? bfhi(word) : bflo(word);
        uint4 u0 = hp[(size_t)s * 16 + 2 * q8];
        uint4 u1 = hp[(size_t)s * 16 + 2 * q8 + 1];
        a[0]  = fmaf(w, bflo(u0.x), a[0]);  a[1]  = fmaf(w, bfhi(u0.x), a[1]);
        a[2]  = fmaf(w, bflo(u0.y), a[2]);  a[3]  = fmaf(w, bfhi(u0.y), a[3]);
        a[4]  = fmaf(w, bflo(u0.z), a[4]);  a[5]  = fmaf(w, bfhi(u0.z), a[5]);
        a[6]  = fmaf(w, bflo(u0.w), a[6]);  a[7]  = fmaf(w, bfhi(u0.w), a[7]);
        a[8]  = fmaf(w, bflo(u1.x), a[8]);  a[9]  = fmaf(w, bfhi(u1.x), a[9]);
        a[10] = fmaf(w, bflo(u1.y), a[10]); a[11] = fmaf(w, bfhi(u1.y), a[11]);
        a[12] = fmaf(w, bflo(u1.z), a[12]); a[13] = fmaf(w, bfhi(u1.z), a[13]);
        a[14] = fmaf(w, bflo(u1.w), a[14]); a[15] = fmaf(w, bfhi(u1.w), a[15]);
        sw += w;
    }
#pragma unroll
    for (int j = 0; j < 16; ++j) {
        a[j] += __shfl_xor(a[j], 8, 64);
        a[j] += __shfl_xor(a[j], 16, 64);
        a[j] += __shfl_xor(a[j], 32, 64);
    }
    sw += __shfl_xor(sw, 8, 64);
    sw += __shfl_xor(sw, 16, 64);
    sw += __shfl_xor(sw, 32, 64);

    if (og == 0) {
        float inv = 1.f / (sw + 1e-16f);
        int d0 = q8 * 16;
        float* ob = &out[(size_t)n * 128 + d0];
#pragma unroll
        for (int c4 = 0; c4 < 4; ++c4) {
            float4 bv = *(const float4*)&bias[d0 + c4 * 4];
            float r0 = fmaf(a[c4 * 4 + 0], inv, bv.x);
            float r1 = fmaf(a[c4 * 4 + 1], inv, bv.y);
            float r2 = fmaf(a[c4 * 4 + 2], inv, bv.z);
            float r3 = fmaf(a[c4 * 4 + 3], inv, bv.w);
            r0 = r0 > 0.f ? r0 : __expf(r0) - 1.f;
            r1 = r1 > 0.f ? r1 : __expf(r1) - 1.f;
            r2 = r2 > 0.f ? r2 : __expf(r2) - 1.f;
            r3 = r3 > 0.f ? r3 : __expf(r3) - 1.f;
            *(float4*)&ob[c4 * 4] = make_float4(r0, r1, r2, r3);
        }
    }
}

// ---------------- launch ----------------
extern "C" void kernel_launch(void* const* d_in, const int* in_sizes, int n_in,
                              void* d_out, int out_size, void* d_ws, size_t ws_size,
                              hipStream_t stream) {
    const float* x     = (const float*)d_in[0];
    const int*   ei    = (const int*)d_in[1];     // int32 [2][E] flat
    const float* W     = (const float*)d_in[2];
    const float* att_s = (const float*)d_in[3];
    const float* att_d = (const float*)d_in[4];
    const float* bias  = (const float*)d_in[5];
    float* out = (float*)d_out;

    int N = in_sizes[0] / 128;
    int E = in_sizes[1] / 2;
    int total = E + N;

    int nps = (N + NB - 1) / NB;                  // 391 (<512 for 9-bit pack)
    float inv_nps = 1.0f / (float)nps;
    int chunk = (total + NBLK - 1) / NBLK;        // ~3322 (<= OSCAP)

    auto align256 = [](size_t v) { return (v + 255) & ~(size_t)255; };
    char* wsp = (char*)d_ws;
    size_t off = 0;
    auto alloc = [&](size_t bytes) {
        char* p = wsp + off;
        off += align256(bytes);
        return p;
    };
    unsigned short* h  = (unsigned short*)alloc((size_t)N * 128 * 2);   // row-major
    float* as        = (float*)alloc((size_t)N * 16);
    float* ad        = (float*)alloc((size_t)N * 16);
    int*   cntT      = (int*)alloc((size_t)NB * NBLK * 4);
    int*   fragRow   = (int*)alloc((size_t)NBLK * NB * 4);
    unsigned* pairs  = (unsigned*)alloc((size_t)NBLK * chunk * 4);
    int*   csrc      = (int*)alloc((size_t)total * 4);
    uint2* wbuf      = (uint2*)alloc((size_t)total * 8);
    int*   rowptr    = (int*)alloc((size_t)(N + 1) * 4);
    (void)ws_size;

    int nGemm = (N + 127) / 128;                  // 782

    k_gemm_sortA<<<NBLK + nGemm, 256, 0, stream>>>(x, W, h, N, ei, E, N, nps, inv_nps,
                                                   cntT, fragRow, pairs, chunk,
                                                   att_s, att_d, as, ad);
    k_binB<<<NB, 512, 0, stream>>>(pairs, cntT, fragRow, csrc, wbuf, rowptr,
                                   as, ad, N, nps, chunk);
    k_agg<<<(N + 3) / 4, 256, 0, stream>>>(h, rowptr, csrc, wbuf, bias, out, N);
}

// Round 21
// 167.054 us; speedup vs baseline: 1.9775x; 1.8468x over previous
//
#include <hip/hip_runtime.h>
#include <math.h>

#define NEG_SLOPE_F 0.2f
#define NB    256     // dst buckets
#define NBLK  512     // binning chunk blocks
#define OSCAP 3328    // LDS cap >= chunk = ceil((E+N)/NBLK)

typedef __attribute__((ext_vector_type(8)))  short short8;
typedef __attribute__((ext_vector_type(16))) float f32x16;

static __device__ __forceinline__ float lrelu(float x) {
    return x > 0.f ? x : NEG_SLOPE_F * x;
}
static __device__ __forceinline__ unsigned f2bf(float f) {
    unsigned u = __float_as_uint(f);
    return (u + 0x7FFFu + ((u >> 16) & 1u)) >> 16;
}
static __device__ __forceinline__ float bflo(unsigned w) { return __uint_as_float(w << 16); }
static __device__ __forceinline__ float bfhi(unsigned w) { return __uint_as_float(w & 0xFFFF0000u); }

static __device__ __forceinline__ int bucket_of(int d, int nps, float inv_nps) {
    int b = (int)((float)d * inv_nps);
    if (d < b * nps) --b;
    else if (d >= (b + 1) * nps) ++b;
    return b;
}

// ---------------- fused L1: countSort (blocks [0,NBLK)) + MFMA GEMM ---------
// sort: one global pass -> LDS stage+hist, LDS scatter, coalesced stream-out.
// gemm: h row-major bf16, W read direct (round-16 proven).
__global__ __launch_bounds__(256) void k_gemm_sortA(
        const float* __restrict__ x, const float* __restrict__ W,
        unsigned short* __restrict__ h, int M,
        const int* __restrict__ ei, int E, int N, int nps, float inv_nps,
        int* __restrict__ cntT, int* __restrict__ fragRow,
        unsigned* __restrict__ pairs, int chunk) {
    int bid = (int)blockIdx.x;
    int tid = threadIdx.x;

    if (bid < NBLK) {
        // ---- counting sort of this block's edge chunk ----
        __shared__ unsigned stage[OSCAP];
        __shared__ unsigned osort[OSCAP];
        __shared__ unsigned char sbkt[OSCAP];
        __shared__ int hist[NB];
        __shared__ int sm[NB];
        __shared__ int cur[NB];
        hist[tid] = 0;
        __syncthreads();
        int total = E + N;
        int lo = bid * chunk;
        int hi = lo + chunk; if (hi > total) hi = total;
        int cnt = hi - lo;
        for (int j = tid; j < cnt; j += 256) {
            int t = lo + j;
            int s, d;
            if (t < E) { s = ei[t]; d = ei[E + t]; }
            else       { s = t - E; d = s; }
            unsigned pk = 0xFFFFFFFFu;
            int b = 0;
            if ((unsigned)s < (unsigned)N && (unsigned)d < (unsigned)N) {
                b = bucket_of(d, nps, inv_nps);
                pk = ((unsigned)s << 9) | (unsigned)(d - b * nps);
                atomicAdd(&hist[b], 1);
            }
            stage[j] = pk;
            sbkt[j] = (unsigned char)b;
        }
        __syncthreads();
        int v = hist[tid];
        sm[tid] = v;
        __syncthreads();
        int acc = v;
        for (int off = 1; off < 256; off <<= 1) {
            int o = (tid >= (unsigned)off) ? sm[tid - off] : 0;
            __syncthreads();
            acc += o; sm[tid] = acc; __syncthreads();
        }
        int excl = acc - v;
        fragRow[bid * NB + tid] = excl;
        cntT[tid * NBLK + bid] = v;
        cur[tid] = excl;
        __syncthreads();
        for (int j = tid; j < cnt; j += 256) {
            unsigned pk = stage[j];
            if (pk == 0xFFFFFFFFu) continue;
            int b = sbkt[j];
            int pos = atomicAdd(&cur[b], 1);
            osort[pos] = pk;
        }
        __syncthreads();
        int m = cur[NB - 1];
        unsigned* pout = pairs + (size_t)bid * chunk;
        for (int j = tid; j < m; j += 256)
            pout[j] = osort[j];
        return;
    }

    // ---- MFMA GEMM: 128x128 per block, 4 waves x 32 rows, W read direct ----
    int gb = bid - NBLK;
    int w = tid >> 6;
    int lane = tid & 63;
    int l31 = lane & 31;
    int lh = lane >> 5;
    int row0 = gb * 128 + w * 32;

    f32x16 acc0, acc1, acc2, acc3;
#pragma unroll
    for (int i = 0; i < 16; ++i) { acc0[i] = 0.f; acc1[i] = 0.f; acc2[i] = 0.f; acc3[i] = 0.f; }

    int arow = row0 + l31;
    if (arow >= M) arow = M - 1;

    for (int k0 = 0; k0 < 128; k0 += 16) {
        int kb = k0 + lh * 8;
        float4 v0 = *(const float4*)&x[(size_t)arow * 128 + kb];
        float4 v1 = *(const float4*)&x[(size_t)arow * 128 + kb + 4];
        short8 a;
        a[0] = (short)f2bf(v0.x); a[1] = (short)f2bf(v0.y);
        a[2] = (short)f2bf(v0.z); a[3] = (short)f2bf(v0.w);
        a[4] = (short)f2bf(v1.x); a[5] = (short)f2bf(v1.y);
        a[6] = (short)f2bf(v1.z); a[7] = (short)f2bf(v1.w);
        short8 b0, b1, b2, b3;
#pragma unroll
        for (int j = 0; j < 8; ++j) {
            const float* wr = &W[(size_t)(kb + j) * 128];
            b0[j] = (short)f2bf(wr[  0 + l31]);
            b1[j] = (short)f2bf(wr[ 32 + l31]);
            b2[j] = (short)f2bf(wr[ 64 + l31]);
            b3[j] = (short)f2bf(wr[ 96 + l31]);
        }
        acc0 = __builtin_amdgcn_mfma_f32_32x32x16_bf16(a, b0, acc0, 0, 0, 0);
        acc1 = __builtin_amdgcn_mfma_f32_32x32x16_bf16(a, b1, acc1, 0, 0, 0);
        acc2 = __builtin_amdgcn_mfma_f32_32x32x16_bf16(a, b2, acc2, 0, 0, 0);
        acc3 = __builtin_amdgcn_mfma_f32_32x32x16_bf16(a, b3, acc3, 0, 0, 0);
    }
#pragma unroll
    for (int reg = 0; reg < 16; ++reg) {
        int row = row0 + (reg & 3) + 8 * (reg >> 2) + 4 * lh;
        if (row < M) {
            size_t rb = (size_t)row * 128;
            h[rb +  0 + l31] = (unsigned short)f2bf(acc0[reg]);
            h[rb + 32 + l31] = (unsigned short)f2bf(acc1[reg]);
            h[rb + 64 + l31] = (unsigned short)f2bf(acc2[reg]);
            h[rb + 96 + l31] = (unsigned short)f2bf(acc3[reg]);
        }
    }
}

// ---------------- fused L2: binB (2 fragments/thread) + att (64 nodes/blk) --
__global__ __launch_bounds__(256) void k_binB_att(
        const unsigned* __restrict__ pairs,
        const int* __restrict__ cntT, const int* __restrict__ fragRow,
        int* __restrict__ csrc, int* __restrict__ rowptr,
        const unsigned short* __restrict__ h,
        const float* __restrict__ att_s, const float* __restrict__ att_d,
        float* __restrict__ as, float* __restrict__ ad,
        int N, int nps, int chunk) {
    int bid = (int)blockIdx.x;
    int t = threadIdx.x;

    if (bid >= NB) {
        // ---- att role: 64 nodes per block (16 iterations of 4 nodes) ----
        int j = t & 63;
        int n0 = (bid - NB) * 64 + (t >> 6);
        float s0 = att_s[2 * j], s1 = att_s[2 * j + 1];
        float d0 = att_d[2 * j], d1 = att_d[2 * j + 1];
#pragma unroll 4
        for (int it = 0; it < 16; ++it) {
            int n = n0 + it * 4;
            if (n >= N) break;
            unsigned u = ((const unsigned*)h)[(size_t)n * 64 + j];
            float lo = bflo(u), hi = bfhi(u);
            float ps = lo * s0 + hi * s1;
            float pd = lo * d0 + hi * d1;
#pragma unroll
            for (int off = 8; off >= 1; off >>= 1) {
                ps += __shfl_xor(ps, off, 64);
                pd += __shfl_xor(pd, off, 64);
            }
            if ((j & 15) == 0) {
                int hh = j >> 4;
                as[n * 4 + hh] = ps;
                ad[n * 4 + hh] = pd;
            }
        }
        return;
    }

    // ---- binB role ----
    __shared__ int hist[512];
    __shared__ int rpt[512];
    __shared__ int sm[256];
    __shared__ int tot_s;
    int b = bid;

    int partial = 0;
#pragma unroll 8
    for (int bp = 0; bp < b; ++bp)
        partial += cntT[bp * NBLK + t] + cntT[bp * NBLK + t + 256];
    sm[t] = partial;
    __syncthreads();
    for (int off = 128; off >= 1; off >>= 1) {
        if (t < off) sm[t] += sm[t + off];
        __syncthreads();
    }
    int bbase = sm[0];
    __syncthreads();

    hist[t] = 0; hist[t + 256] = 0;
    __syncthreads();

    int fo0 = t * chunk + fragRow[t * NB + b];
    int fc0 = cntT[b * NBLK + t];
    int fo1 = (t + 256) * chunk + fragRow[(t + 256) * NB + b];
    int fc1 = cntT[b * NBLK + t + 256];

    for (int j = 0; j < fc0; ++j)
        atomicAdd(&hist[pairs[(size_t)fo0 + j] & 511], 1);
    for (int j = 0; j < fc1; ++j)
        atomicAdd(&hist[pairs[(size_t)fo1 + j] & 511], 1);
    __syncthreads();

    int e0 = hist[2 * t], e1 = hist[2 * t + 1];
    int ps2 = e0 + e1;
    sm[t] = ps2;
    __syncthreads();
    int acc = ps2;
    for (int off = 1; off < 256; off <<= 1) {
        int o = (t >= (unsigned)off) ? sm[t - off] : 0;
        __syncthreads();
        acc += o; sm[t] = acc; __syncthreads();
    }
    int excl = acc - ps2;
    rpt[2 * t] = excl;
    rpt[2 * t + 1] = excl + e0;
    if (t == 255) tot_s = excl + e0 + e1;
    __syncthreads();
    hist[t] = rpt[t]; hist[t + 256] = rpt[t + 256];
    __syncthreads();

    for (int j = 0; j < fc0; ++j) {
        unsigned pk = pairs[(size_t)fo0 + j];
        int pos = atomicAdd(&hist[pk & 511], 1);
        csrc[bbase + pos] = (int)(pk >> 9);
    }
    for (int j = 0; j < fc1; ++j) {
        unsigned pk = pairs[(size_t)fo1 + j];
        int pos = atomicAdd(&hist[pk & 511], 1);
        csrc[bbase + pos] = (int)(pk >> 9);
    }

    for (int k = t; k < nps; k += 256) {
        int n = b * nps + k;
        if (n < N) rowptr[n] = bbase + rpt[k];
    }
    if (b == NB - 1 && t == 0) rowptr[N] = bbase + tot_s;
}

// ---------------- aggregate: 8 edges in flight (eighth-wave, 2x uint4) ------
__global__ __launch_bounds__(256) void k_agg(const unsigned short* __restrict__ h,
                                             const int* __restrict__ rowptr, const int* __restrict__ csrc,
                                             const float* __restrict__ as, const float* __restrict__ ad,
                                             const float* __restrict__ bias,
                                             float* __restrict__ out, int N) {
    int wv = threadIdx.x >> 6;
    int lane = threadIdx.x & 63;
    int n = blockIdx.x * 4 + wv;
    if (n >= N) return;
    int og = lane >> 3;            // edge slot 0..7
    int q8 = lane & 7;             // dims 16*q8 .. 16*q8+15
    int head = q8 >> 1;

    int o0 = rowptr[n];
    int deg = rowptr[n + 1] - o0;
    float adh = ad[(size_t)n * 4 + head];

    const uint4* hp = (const uint4*)h;   // 16 uint4 per row
    float a[16];
#pragma unroll
    for (int j = 0; j < 16; ++j) a[j] = 0.f;
    float sw = 0.f;

    for (int i = og; i < deg; i += 8) {
        int s = csrc[o0 + i];
        float e = lrelu(as[(size_t)s * 4 + head] + adh);
        float w = __expf(e);
        uint4 u0 = hp[(size_t)s * 16 + 2 * q8];
        uint4 u1 = hp[(size_t)s * 16 + 2 * q8 + 1];
        a[0]  = fmaf(w, bflo(u0.x), a[0]);  a[1]  = fmaf(w, bfhi(u0.x), a[1]);
        a[2]  = fmaf(w, bflo(u0.y), a[2]);  a[3]  = fmaf(w, bfhi(u0.y), a[3]);
        a[4]  = fmaf(w, bflo(u0.z), a[4]);  a[5]  = fmaf(w, bfhi(u0.z), a[5]);
        a[6]  = fmaf(w, bflo(u0.w), a[6]);  a[7]  = fmaf(w, bfhi(u0.w), a[7]);
        a[8]  = fmaf(w, bflo(u1.x), a[8]);  a[9]  = fmaf(w, bfhi(u1.x), a[9]);
        a[10] = fmaf(w, bflo(u1.y), a[10]); a[11] = fmaf(w, bfhi(u1.y), a[11]);
        a[12] = fmaf(w, bflo(u1.z), a[12]); a[13] = fmaf(w, bfhi(u1.z), a[13]);
        a[14] = fmaf(w, bflo(u1.w), a[14]); a[15] = fmaf(w, bfhi(u1.w), a[15]);
        sw += w;
    }
#pragma unroll
    for (int j = 0; j < 16; ++j) {
        a[j] += __shfl_xor(a[j], 8, 64);
        a[j] += __shfl_xor(a[j], 16, 64);
        a[j] += __shfl_xor(a[j], 32, 64);
    }
    sw += __shfl_xor(sw, 8, 64);
    sw += __shfl_xor(sw, 16, 64);
    sw += __shfl_xor(sw, 32, 64);

    if (og == 0) {
        float inv = 1.f / (sw + 1e-16f);
        int d0 = q8 * 16;
        float* ob = &out[(size_t)n * 128 + d0];
#pragma unroll
        for (int c4 = 0; c4 < 4; ++c4) {
            float4 bv = *(const float4*)&bias[d0 + c4 * 4];
            float r0 = fmaf(a[c4 * 4 + 0], inv, bv.x);
            float r1 = fmaf(a[c4 * 4 + 1], inv, bv.y);
            float r2 = fmaf(a[c4 * 4 + 2], inv, bv.z);
            float r3 = fmaf(a[c4 * 4 + 3], inv, bv.w);
            r0 = r0 > 0.f ? r0 : __expf(r0) - 1.f;
            r1 = r1 > 0.f ? r1 : __expf(r1) - 1.f;
            r2 = r2 > 0.f ? r2 : __expf(r2) - 1.f;
            r3 = r3 > 0.f ? r3 : __expf(r3) - 1.f;
            *(float4*)&ob[c4 * 4] = make_float4(r0, r1, r2, r3);
        }
    }
}

// ---------------- launch ----------------
extern "C" void kernel_launch(void* const* d_in, const int* in_sizes, int n_in,
                              void* d_out, int out_size, void* d_ws, size_t ws_size,
                              hipStream_t stream) {
    const float* x     = (const float*)d_in[0];
    const int*   ei    = (const int*)d_in[1];     // int32 [2][E] flat
    const float* W     = (const float*)d_in[2];
    const float* att_s = (const float*)d_in[3];
    const float* att_d = (const float*)d_in[4];
    const float* bias  = (const float*)d_in[5];
    float* out = (float*)d_out;

    int N = in_sizes[0] / 128;
    int E = in_sizes[1] / 2;
    int total = E + N;

    int nps = (N + NB - 1) / NB;                  // 391 (<512 for 9-bit pack)
    float inv_nps = 1.0f / (float)nps;
    int chunk = (total + NBLK - 1) / NBLK;        // ~3322 (<= OSCAP)

    auto align256 = [](size_t v) { return (v + 255) & ~(size_t)255; };
    char* wsp = (char*)d_ws;
    size_t off = 0;
    auto alloc = [&](size_t bytes) {
        char* p = wsp + off;
        off += align256(bytes);
        return p;
    };
    unsigned short* h  = (unsigned short*)alloc((size_t)N * 128 * 2);
    float* as        = (float*)alloc((size_t)N * 16);
    float* ad        = (float*)alloc((size_t)N * 16);
    int*   cntT      = (int*)alloc((size_t)NB * NBLK * 4);
    int*   fragRow   = (int*)alloc((size_t)NBLK * NB * 4);
    unsigned* pairs  = (unsigned*)alloc((size_t)NBLK * chunk * 4);
    int*   csrc      = (int*)alloc((size_t)total * 4);
    int*   rowptr    = (int*)alloc((size_t)(N + 1) * 4);
    (void)ws_size;

    int nGemm = (N + 127) / 128;                  // 782
    int nAtt  = (N + 63) / 64;                    // 1563 (64 nodes per block)

    k_gemm_sortA<<<NBLK + nGemm, 256, 0, stream>>>(x, W, h, N, ei, E, N, nps, inv_nps,
                                                   cntT, fragRow, pairs, chunk);
    k_binB_att<<<NB + nAtt, 256, 0, stream>>>(pairs, cntT, fragRow, csrc, rowptr,
                                              h, att_s, att_d, as, ad, N, nps, chunk);
    k_agg<<<(N + 3) / 4, 256, 0, stream>>>(h, rowptr, csrc, as, ad, bias, out, N);
}